// Round 1
// baseline (486.803 us; speedup 1.0000x reference)
//
#include <hip/hip_runtime.h>

// ---------------------------------------------------------------------------
// BlockSparseAttention (block-local attention), MI355X fp16-MFMA pipeline.
//   x[4,4096,1024] fp32; Wq/Wk/Wv/Wo[1024,1024] fp32; b*[1024] fp32
//   out[4,4096,1024] fp32
// Pipeline: (1) convert x -> fp16 (perm layout), W -> fp16 transposed (perm)
//           (2) fused QKV GEMM + block attention per (token-block, head)
//           (3) out-projection GEMM (fp32 out + bias)
// Storage transform for all fp16 MFMA operand matrices: within each 32-col
// group, element k = 4g+b+16h stored at position p = 8g+4h+b, so each lane's
// 8-half fragment (k = {4g..4g+3} U {16+4g..19+4g}) is 16 contiguous bytes.
// Both MFMA operands use the same transform -> result invariant to the exact
// HW slot->k map (requires only A/B layout symmetry, standard on CDNA).
// Workspace: needs >= 72 MB (xh 32MB | 4x Wt 2MB | ao 32MB).
// ---------------------------------------------------------------------------

typedef _Float16 h16;
typedef _Float16 half8 __attribute__((ext_vector_type(8)));
typedef _Float16 half4 __attribute__((ext_vector_type(4)));
typedef float    f32x4 __attribute__((ext_vector_type(4)));
typedef float    fvec4 __attribute__((ext_vector_type(4)));

__device__ __forceinline__ void gload16(const void* g, void* l) {
  __builtin_amdgcn_global_load_lds(
      (const __attribute__((address_space(1))) unsigned int*)g,
      (__attribute__((address_space(3))) unsigned int*)l, 16, 0, 0);
}

#define MFMA16(a, b, c) __builtin_amdgcn_mfma_f32_16x16x32_f16(a, b, c, 0, 0, 0)

// ---------------- kernel 1a: x fp32 -> fp16, permuted ----------------------
__global__ __launch_bounds__(256) void k_cvt_x(const float* __restrict__ x,
                                               h16* __restrict__ xh) {
  size_t t = (size_t)blockIdx.x * 256 + threadIdx.x;  // 524288 threads, 32 elems each
  const fvec4* src = (const fvec4*)(x + t * 32);
  fvec4 f[8];
#pragma unroll
  for (int m = 0; m < 8; ++m) f[m] = src[m];
  half8* dst = (half8*)(xh + t * 32);
#pragma unroll
  for (int g = 0; g < 4; ++g) {
    half8 o;
#pragma unroll
    for (int j = 0; j < 4; ++j) { o[j] = (h16)f[g][j]; o[4 + j] = (h16)f[g + 4][j]; }
    dst[g] = o;
  }
}

// ------------- kernel 1b: W[k][n] fp32 -> Wt[n][k] fp16, permuted ----------
__global__ __launch_bounds__(256) void k_cvt_w(const float* __restrict__ W,
                                               h16* __restrict__ Wt) {
  __shared__ float T[64][33];
  int bid = blockIdx.x;                 // 512 per matrix
  int n0 = (bid & 31) * 32;
  int k0 = (bid >> 5) * 64;
  int tid = threadIdx.x;
#pragma unroll
  for (int it = 0; it < 2; ++it) {
    int s = it * 256 + tid;             // 0..511
    int r = s >> 3, c4 = s & 7;         // 64 rows x 8 float4
    fvec4 v = *(const fvec4*)(W + (size_t)(k0 + r) * 1024 + n0 + c4 * 4);
#pragma unroll
    for (int j = 0; j < 4; ++j) T[r][c4 * 4 + j] = v[j];
  }
  __syncthreads();
  int n = tid >> 3, j = tid & 7;        // 32 n x 8 16B-blocks
  int kb = j >> 2, g = j & 3;
  half8 o;
#pragma unroll
  for (int h = 0; h < 2; ++h)
#pragma unroll
    for (int b = 0; b < 4; ++b)
      o[h * 4 + b] = (h16)T[kb * 32 + 4 * g + 16 * h + b][n];
  *(half8*)(Wt + (size_t)(n0 + n) * 1024 + k0 + kb * 32 + g * 8) = o;
}

// ---------- kernel 2: fused QKV projection + block-local attention ---------
// grid = 2048 WGs: XCD-chunked: head = (bid&7)*2 + (r>>7), blk = r&127
// WG = 256 thr = 4 waves; wave w owns q-rows [w*32, w*32+32)
__global__ __launch_bounds__(256) void k_qkv_attn(
    const h16* __restrict__ xh, const h16* __restrict__ Wtq,
    const h16* __restrict__ Wtk, const h16* __restrict__ Wtv,
    const float* __restrict__ bq, const float* __restrict__ bk,
    const float* __restrict__ bv, h16* __restrict__ ao) {
  __shared__ union {
    struct { h16 A[128 * 32]; h16 B[192 * 32]; } g;           // GEMM tiles (20.5KB)
    struct { h16 K[128 * 72]; h16 V[64 * 136]; h16 Q[4 * 32 * 72]; } a;  // 54.3KB
  } sm;
  int bid = blockIdx.x;
  int r2 = bid >> 3;
  int h = (bid & 7) * 2 + (r2 >> 7);
  int blk = r2 & 127;
  int tid = threadIdx.x;
  int w = tid >> 6, lane = tid & 63;
  int l15 = lane & 15, g4 = lane >> 4;
  size_t row0 = (size_t)blk * 128;

  f32x4 acc[2][12];
#pragma unroll
  for (int mi = 0; mi < 2; ++mi)
#pragma unroll
    for (int nj = 0; nj < 12; ++nj) acc[mi][nj] = (f32x4){0.f, 0.f, 0.f, 0.f};

  // ---- QKV projection: C[128 x 192] = x_blk[128 x 1024] * [Wq|Wk|Wv] slice
  for (int kt = 0; kt < 32; ++kt) {
#pragma unroll
    for (int j = 0; j < 2; ++j) {            // stage A: 512 x 16B slots
      int s = j * 256 + tid;
      int r = s >> 2, t4 = s & 3;
      gload16(xh + (row0 + r) * 1024 + kt * 32 + t4 * 8,
              &sm.g.A[(size_t)(j * 256 + w * 64) * 8]);
    }
#pragma unroll
    for (int m = 0; m < 3; ++m) {            // stage B: 768 x 16B slots
      int s = m * 256 + tid;
      int r = s >> 2, t4 = s & 3;            // r 0..191
      const h16* wp = (r < 64) ? Wtq : ((r < 128) ? Wtk : Wtv);
      gload16(wp + (size_t)(h * 64 + (r & 63)) * 1024 + kt * 32 + t4 * 8,
              &sm.g.B[(size_t)(m * 256 + w * 64) * 8]);
    }
    __syncthreads();
    half8 a[2];
#pragma unroll
    for (int mi = 0; mi < 2; ++mi)
      a[mi] = *(const half8*)&sm.g.A[(w * 32 + mi * 16 + l15) * 32 + g4 * 8];
#pragma unroll
    for (int nj = 0; nj < 12; ++nj) {
      half8 b = *(const half8*)&sm.g.B[(nj * 16 + l15) * 32 + g4 * 8];
      acc[0][nj] = MFMA16(a[0], b, acc[0][nj]);
      acc[1][nj] = MFMA16(a[1], b, acc[1][nj]);
    }
    __syncthreads();
  }

  // ---- bias + move Q,K,V to LDS (K:[kv][d-perm], V:[d][kv-perm], Q per-wave)
  const float sc = 0.125f * 1.44269504088896f;  // 1/sqrt(dk) * log2(e)
#pragma unroll
  for (int mi = 0; mi < 2; ++mi) {
#pragma unroll
    for (int nj = 0; nj < 12; ++nj) {
      int d = (nj & 3) * 16 + l15;             // 0..63
      constexpr int dummy = 0; (void)dummy;
      if (nj < 4) {                            // Q
        float bias = bq[h * 64 + d];
        int pd = 32 * ((nj >> 1) & 1) + 8 * (l15 >> 2) + 4 * (nj & 1) + (l15 & 3);
        h16* Qw = &sm.a.Q[w * 32 * 72];
#pragma unroll
        for (int r = 0; r < 4; ++r)
          Qw[(mi * 16 + 4 * g4 + r) * 72 + pd] = (h16)((acc[mi][nj][r] + bias) * sc);
      } else if (nj < 8) {                     // K
        float bias = bk[h * 64 + d];
        int pd = 32 * ((nj >> 1) & 1) + 8 * (l15 >> 2) + 4 * (nj & 1) + (l15 & 3);
        int kv = w * 32 + mi * 16 + 4 * g4;
#pragma unroll
        for (int r = 0; r < 4; ++r)
          sm.a.K[(kv + r) * 72 + pd] = (h16)(acc[mi][nj][r] + bias);
      } else {                                 // V (transposed store)
        float bias = bv[h * 64 + d];
        half4 v4;
#pragma unroll
        for (int r = 0; r < 4; ++r) v4[r] = (h16)(acc[mi][nj][r] + bias);
        // kv = w*32 + mi*16 + 4*g4 + r -> block w, p = 8*g4 + 4*mi + r
        *(half4*)&sm.a.V[d * 136 + w * 32 + 8 * g4 + 4 * mi] = v4;
      }
    }
  }
  __syncthreads();

  // ---- S^T = K * Q^T  (rows kv 0..127, cols = this wave's 32 q)
  f32x4 sacc[8][2];
#pragma unroll
  for (int Rf = 0; Rf < 8; ++Rf)
#pragma unroll
    for (int cf = 0; cf < 2; ++cf) sacc[Rf][cf] = (f32x4){0.f, 0.f, 0.f, 0.f};
  const h16* Qw = &sm.a.Q[w * 32 * 72];
#pragma unroll
  for (int kt2 = 0; kt2 < 2; ++kt2) {
    half8 qb[2];
#pragma unroll
    for (int cf = 0; cf < 2; ++cf)
      qb[cf] = *(const half8*)&Qw[(cf * 16 + l15) * 72 + kt2 * 32 + g4 * 8];
#pragma unroll
    for (int Rf = 0; Rf < 8; ++Rf) {
      half8 ka = *(const half8*)&sm.a.K[(Rf * 16 + l15) * 72 + kt2 * 32 + g4 * 8];
      sacc[Rf][0] = MFMA16(ka, qb[0], sacc[Rf][0]);
      sacc[Rf][1] = MFMA16(ka, qb[1], sacc[Rf][1]);
    }
  }

  // ---- softmax over kv (rows of S^T): lane-local 32 + shfl_xor 16,32
  float rmax[2] = {-1e30f, -1e30f};
#pragma unroll
  for (int Rf = 0; Rf < 8; ++Rf)
#pragma unroll
    for (int cf = 0; cf < 2; ++cf)
#pragma unroll
      for (int r = 0; r < 4; ++r) rmax[cf] = fmaxf(rmax[cf], sacc[Rf][cf][r]);
#pragma unroll
  for (int cf = 0; cf < 2; ++cf) {
    rmax[cf] = fmaxf(rmax[cf], __shfl_xor(rmax[cf], 16, 64));
    rmax[cf] = fmaxf(rmax[cf], __shfl_xor(rmax[cf], 32, 64));
  }
  float rsum[2] = {0.f, 0.f};
#pragma unroll
  for (int Rf = 0; Rf < 8; ++Rf)
#pragma unroll
    for (int cf = 0; cf < 2; ++cf)
#pragma unroll
      for (int r = 0; r < 4; ++r) {
        float p = exp2f(sacc[Rf][cf][r] - rmax[cf]);
        sacc[Rf][cf][r] = p;
        rsum[cf] += p;
      }
#pragma unroll
  for (int cf = 0; cf < 2; ++cf) {
    rsum[cf] += __shfl_xor(rsum[cf], 16, 64);
    rsum[cf] += __shfl_xor(rsum[cf], 32, 64);
    rsum[cf] = 1.0f / rsum[cf];
  }

  // ---- O^T = V^T * P^T  (P^T C-frags are directly the B-frags, zero restage)
  f32x4 oacc[4][2];
#pragma unroll
  for (int dR = 0; dR < 4; ++dR)
#pragma unroll
    for (int cf = 0; cf < 2; ++cf) oacc[dR][cf] = (f32x4){0.f, 0.f, 0.f, 0.f};
#pragma unroll
  for (int kb = 0; kb < 4; ++kb) {
    half8 pb[2];
#pragma unroll
    for (int cf = 0; cf < 2; ++cf) {
      half8 t;
#pragma unroll
      for (int hb = 0; hb < 8; ++hb)
        t[hb] = (h16)sacc[2 * kb + (hb >> 2)][cf][hb & 3];
      pb[cf] = t;
    }
#pragma unroll
    for (int dR = 0; dR < 4; ++dR) {
      half8 va = *(const half8*)&sm.a.V[(dR * 16 + l15) * 136 + kb * 32 + g4 * 8];
      oacc[dR][0] = MFMA16(va, pb[0], oacc[dR][0]);
      oacc[dR][1] = MFMA16(va, pb[1], oacc[dR][1]);
    }
  }

  // ---- write attn_out fp16 in permuted layout (A-operand of out-GEMM)
#pragma unroll
  for (int dR = 0; dR < 4; ++dR)
#pragma unroll
    for (int cf = 0; cf < 2; ++cf) {
      size_t token = row0 + w * 32 + cf * 16 + l15;
      half4 v4;
#pragma unroll
      for (int r = 0; r < 4; ++r) v4[r] = (h16)(oacc[dR][cf][r] * rsum[cf]);
      // col = h*64 + 16*dR + 4*g4 + r -> block 2h+(dR>>1), p = 8g4+4(dR&1)+r
      *(half4*)&ao[token * 1024 + 32 * (2 * h + (dR >> 1)) + 8 * g4 + 4 * (dR & 1)] = v4;
    }
}

// ----------------- kernel 3: out = ao * Wo^T + bo (fp32) -------------------
__global__ __launch_bounds__(256) void k_outproj(
    const h16* __restrict__ ao, const h16* __restrict__ Wto,
    const float* __restrict__ bo, float* __restrict__ out) {
  __shared__ h16 A[128 * 32];
  __shared__ h16 B[128 * 32];
  int bid = blockIdx.x;                         // 1024
  int tile = (bid & 7) * 128 + (bid >> 3);      // XCD-chunked
  int mt = tile >> 3, nt = tile & 7;
  size_t m0 = (size_t)mt * 128;
  int n0 = nt * 128;
  int tid = threadIdx.x, w = tid >> 6, lane = tid & 63;
  int l15 = lane & 15, g4 = lane >> 4;
  int wr = w >> 1, wc = w & 1;
  f32x4 acc[4][4];
#pragma unroll
  for (int mi = 0; mi < 4; ++mi)
#pragma unroll
    for (int nj = 0; nj < 4; ++nj) acc[mi][nj] = (f32x4){0.f, 0.f, 0.f, 0.f};

  for (int kt = 0; kt < 32; ++kt) {
#pragma unroll
    for (int j = 0; j < 2; ++j) {
      int s = j * 256 + tid;
      int r = s >> 2, t4 = s & 3;
      gload16(ao + (m0 + r) * 1024 + kt * 32 + t4 * 8,
              &A[(size_t)(j * 256 + w * 64) * 8]);
      gload16(Wto + (size_t)(n0 + r) * 1024 + kt * 32 + t4 * 8,
              &B[(size_t)(j * 256 + w * 64) * 8]);
    }
    __syncthreads();
    half8 a[4];
#pragma unroll
    for (int mi = 0; mi < 4; ++mi)
      a[mi] = *(const half8*)&A[(wr * 64 + mi * 16 + l15) * 32 + g4 * 8];
#pragma unroll
    for (int nj = 0; nj < 4; ++nj) {
      half8 b = *(const half8*)&B[(wc * 64 + nj * 16 + l15) * 32 + g4 * 8];
#pragma unroll
      for (int mi = 0; mi < 4; ++mi) acc[mi][nj] = MFMA16(a[mi], b, acc[mi][nj]);
    }
    __syncthreads();
  }
#pragma unroll
  for (int mi = 0; mi < 4; ++mi)
#pragma unroll
    for (int nj = 0; nj < 4; ++nj) {
      int col = n0 + wc * 64 + nj * 16 + l15;
      float bb = bo[col];
      size_t rowb = m0 + wr * 64 + mi * 16 + 4 * g4;
#pragma unroll
      for (int r = 0; r < 4; ++r)
        out[(rowb + r) * 1024 + col] = acc[mi][nj][r] + bb;
    }
}

// ---------------------------------------------------------------------------
extern "C" void kernel_launch(void* const* d_in, const int* in_sizes, int n_in,
                              void* d_out, int out_size, void* d_ws, size_t ws_size,
                              hipStream_t stream) {
  const float* x  = (const float*)d_in[0];
  const float* Wq = (const float*)d_in[1];
  const float* bq = (const float*)d_in[2];
  const float* Wk = (const float*)d_in[3];
  const float* bk = (const float*)d_in[4];
  const float* Wv = (const float*)d_in[5];
  const float* bv = (const float*)d_in[6];
  const float* Wo = (const float*)d_in[7];
  const float* bo = (const float*)d_in[8];
  float* out = (float*)d_out;

  char* ws = (char*)d_ws;                 // needs >= 72 MB
  h16* xh  = (h16*)ws;                    // 32 MB
  h16* wtq = (h16*)(ws + (32u << 20));    // 2 MB each
  h16* wtk = (h16*)(ws + (34u << 20));
  h16* wtv = (h16*)(ws + (36u << 20));
  h16* wto = (h16*)(ws + (38u << 20));
  h16* ao  = (h16*)(ws + (40u << 20));    // 32 MB

  k_cvt_x<<<2048, 256, 0, stream>>>(x, xh);
  k_cvt_w<<<512, 256, 0, stream>>>(Wq, wtq);
  k_cvt_w<<<512, 256, 0, stream>>>(Wk, wtk);
  k_cvt_w<<<512, 256, 0, stream>>>(Wv, wtv);
  k_cvt_w<<<512, 256, 0, stream>>>(Wo, wto);
  k_qkv_attn<<<2048, 256, 0, stream>>>(xh, wtq, wtk, wtv, bq, bk, bv, ao);
  k_outproj<<<1024, 256, 0, stream>>>(ao, wto, bo, out);
}

// Round 2
// 381.042 us; speedup vs baseline: 1.2776x; 1.2776x over previous
//
#include <hip/hip_runtime.h>

// ---------------------------------------------------------------------------
// BlockSparseAttention — de-fused fp16-MFMA pipeline, swizzled layouts.
//  1) k_cvt_x : x fp32 -> xh fp16, swizzled row layout
//  2) k_cvt_w : Wq|Wk|Wv|Wo fp32 -> Wt[n][k] fp16 swizzled (one launch)
//  3) k_gemm_qkv: [16384x1024]x[1024x3072] m97-structure GEMM; epilogue
//     scatters Q,K (row-major packed per (blk,head), bias+scale fused) and
//     V^T (transposed packed) in swizzled fp16 layouts.
//  4) k_attn : per (blk,head), 4 waves, ZERO LDS / ZERO barriers. MFMA frags
//     loaded global->VGPR (48 KB working set is L2-resident).
//     S^T = mfma(K,Q) -> lane-local softmax -> O^T = mfma(V^T, P^T).
//  5) k_outproj: [16384x1024]x[1024x1024] GEMM, fp32 + bias out.
// Swizzle (all fp16 operand matrices): within each row's 64B k-tile (32 k),
// k = 4g+16h+b stored at 16B-slot (g+row)&3, byte (4h+b)*2. gload16 stays a
// linear copy; ds_read_b128/global frag reads are conflict-free (<=2-way).
// Workspace (needs >= 136 MB): [0,32M) xh then ao | [32M,40M) Wt q,k,v,o |
// [40,72) Qp | [72,104) Kp | [104,136) Vp.
// ---------------------------------------------------------------------------

typedef _Float16 h16;
typedef _Float16 half8 __attribute__((ext_vector_type(8)));
typedef _Float16 half4 __attribute__((ext_vector_type(4)));
typedef float    f32x4 __attribute__((ext_vector_type(4)));
typedef float    fvec4 __attribute__((ext_vector_type(4)));

__device__ __forceinline__ void gload16(const void* g, void* l) {
  __builtin_amdgcn_global_load_lds(
      (const __attribute__((address_space(1))) unsigned int*)g,
      (__attribute__((address_space(3))) unsigned int*)l, 16, 0, 0);
}
#define MFMA16(a, b, c) __builtin_amdgcn_mfma_f32_16x16x32_f16(a, b, c, 0, 0, 0)

// ---------------- kernel 1: x fp32 -> fp16, swizzled -----------------------
__global__ __launch_bounds__(256) void k_cvt_x(const float* __restrict__ x,
                                               h16* __restrict__ xh) {
  size_t t = (size_t)blockIdx.x * 256 + threadIdx.x;  // (token, ktile) pairs
  int token = (int)(t >> 5);
  const fvec4* src = (const fvec4*)(x + t * 32);
  fvec4 f[8];
#pragma unroll
  for (int m = 0; m < 8; ++m) f[m] = src[m];
  h16* dst = xh + t * 32;  // = token*1024 + kt*32 halves
#pragma unroll
  for (int t4 = 0; t4 < 4; ++t4) {
    int g = (t4 - token) & 3;
    half8 o;
#pragma unroll
    for (int j = 0; j < 8; ++j) o[j] = (h16)f[g + 4 * (j >> 2)][j & 3];
    *(half8*)(dst + t4 * 8) = o;
  }
}

// ------- kernel 2: W[k][n] fp32 -> Wt[n][k] fp16 swizzled, 4 mats ----------
__global__ __launch_bounds__(256) void k_cvt_w(
    const float* __restrict__ W0, const float* __restrict__ W1,
    const float* __restrict__ W2, const float* __restrict__ W3,
    h16* __restrict__ Wt_all) {
  __shared__ float T[64][33];
  int bid = blockIdx.x;                 // 2048 = 4 mats x 512
  int mat = bid >> 9, b2 = bid & 511;
  const float* W = (mat == 0) ? W0 : (mat == 1) ? W1 : (mat == 2) ? W2 : W3;
  h16* Wt = Wt_all + (size_t)mat * 1024 * 1024;
  int n0 = (b2 & 31) * 32;
  int k0 = (b2 >> 5) * 64;
  int tid = threadIdx.x;
#pragma unroll
  for (int it = 0; it < 2; ++it) {
    int s = it * 256 + tid;
    int r = s >> 3, c4 = s & 7;
    fvec4 v = *(const fvec4*)(W + (size_t)(k0 + r) * 1024 + n0 + c4 * 4);
#pragma unroll
    for (int j = 0; j < 4; ++j) T[r][c4 * 4 + j] = v[j];
  }
  __syncthreads();
  int n = tid >> 3, j = tid & 7;
  int kb = j >> 2, g = j & 3;
  half8 o;
#pragma unroll
  for (int h = 0; h < 2; ++h)
#pragma unroll
    for (int b = 0; b < 4; ++b)
      o[h * 4 + b] = (h16)T[kb * 32 + 4 * g + 16 * h + b][n];
  int nn = n0 + n;
  int slot = (g + nn) & 3;
  *(half8*)(Wt + (size_t)nn * 1024 + ((k0 >> 5) + kb) * 32 + slot * 8) = o;
}

// --------- kernel 3: QKV GEMM 16384x3072, epilogue packs Q/K/V^T -----------
__global__ __launch_bounds__(256) void k_gemm_qkv(
    const h16* __restrict__ xh, const h16* __restrict__ wt,
    const float* __restrict__ bq, const float* __restrict__ bk,
    const float* __restrict__ bv, h16* __restrict__ Qp,
    h16* __restrict__ Kp, h16* __restrict__ Vp) {
  __shared__ h16 A[128 * 32];
  __shared__ h16 B[128 * 32];
  int bid = blockIdx.x;                      // 3072 = 8 XCD x 384
  int t = (bid & 7) * 384 + (bid >> 3);
  int mt = t / 24, nt = t - mt * 24;
  int tid = threadIdx.x, w = tid >> 6, lane = tid & 63;
  int l15 = lane & 15, g4 = lane >> 4;
  int wr = w >> 1, wc = w & 1;
  size_t m0 = (size_t)mt * 128;
  f32x4 acc[4][4] = {};
  for (int kt = 0; kt < 32; ++kt) {
#pragma unroll
    for (int j = 0; j < 2; ++j) {
      int s = j * 256 + tid;
      int r = s >> 2, t4 = s & 3;
      gload16(xh + (m0 + r) * 1024 + kt * 32 + t4 * 8, &A[(j * 256 + w * 64) * 8]);
      gload16(wt + (size_t)(nt * 128 + r) * 1024 + kt * 32 + t4 * 8,
              &B[(j * 256 + w * 64) * 8]);
    }
    __syncthreads();
    half8 a[4], b[4];
#pragma unroll
    for (int mi = 0; mi < 4; ++mi)
      a[mi] = *(const half8*)&A[(wr * 64 + mi * 16 + l15) * 32 + ((g4 + l15) & 3) * 8];
#pragma unroll
    for (int nj = 0; nj < 4; ++nj)
      b[nj] = *(const half8*)&B[(wc * 64 + nj * 16 + l15) * 32 + ((g4 + l15) & 3) * 8];
#pragma unroll
    for (int nj = 0; nj < 4; ++nj)
#pragma unroll
      for (int mi = 0; mi < 4; ++mi) acc[mi][nj] = MFMA16(a[mi], b[nj], acc[mi][nj]);
    __syncthreads();
  }
  // epilogue: scatter to packed per-(blk,head) buffers
  int mat = nt >> 3;                 // 0=Q 1=K 2=V
  int hbase = (nt & 7) * 2;
  int blk = mt;
  const float sc = 0.125f * 1.44269504088896f;  // 1/sqrt(dk)*log2(e)
#pragma unroll
  for (int mi = 0; mi < 4; ++mi)
#pragma unroll
    for (int nj = 0; nj < 4; ++nj) {
      int c = wc * 64 + nj * 16 + l15;
      int head = hbase + (c >> 6), d = c & 63;
      int tok0 = wr * 64 + mi * 16 + g4 * 4;
      size_t bh8k = (size_t)(blk * 16 + head) * 8192;
      if (mat == 0) {
        float bias = bq[head * 64 + d];
        int inner = ((d >> 4) & 1) * 4 + (d & 3), gq = (d & 15) >> 2, dk5 = d >> 5;
#pragma unroll
        for (int r = 0; r < 4; ++r) {
          int tok = tok0 + r;
          Qp[bh8k + tok * 64 + dk5 * 32 + ((gq + tok) & 3) * 8 + inner] =
              (h16)((acc[mi][nj][r] + bias) * sc);
        }
      } else if (mat == 1) {
        float bias = bk[head * 64 + d];
        int inner = ((d >> 4) & 1) * 4 + (d & 3), gq = (d & 15) >> 2, dk5 = d >> 5;
#pragma unroll
        for (int r = 0; r < 4; ++r) {
          int tok = tok0 + r;
          Kp[bh8k + tok * 64 + dk5 * 32 + ((gq + tok) & 3) * 8 + inner] =
              (h16)(acc[mi][nj][r] + bias);
        }
      } else {
        float bias = bv[head * 64 + d];
        half4 v4;
#pragma unroll
        for (int r = 0; r < 4; ++r) v4[r] = (h16)(acc[mi][nj][r] + bias);
        *(half4*)&Vp[bh8k + d * 128 + (tok0 >> 5) * 32 + ((g4 + d) & 3) * 8 +
                     (mi & 1) * 4] = v4;
      }
    }
}

// --------- kernel 4: block attention, zero LDS / zero barriers -------------
__global__ __launch_bounds__(256) void k_attn(
    const h16* __restrict__ Qp, const h16* __restrict__ Kp,
    const h16* __restrict__ Vp, h16* __restrict__ ao) {
  int bh = blockIdx.x;                       // 2048 = 128 blk x 16 heads
  int blk = bh >> 4, head = bh & 15;
  int tid = threadIdx.x, w = tid >> 6, lane = tid & 63;
  int l15 = lane & 15, g4 = lane >> 4;
  const h16* Qb = Qp + (size_t)bh * 8192;
  const h16* Kb = Kp + (size_t)bh * 8192;
  const h16* Vb = Vp + (size_t)bh * 8192;

  half8 qb[2][2];
#pragma unroll
  for (int cf = 0; cf < 2; ++cf)
#pragma unroll
    for (int k2 = 0; k2 < 2; ++k2) {
      int q = w * 32 + cf * 16 + l15;
      qb[cf][k2] = *(const half8*)(Qb + q * 64 + k2 * 32 + ((g4 + q) & 3) * 8);
    }
  f32x4 sacc[8][2] = {};
#pragma unroll
  for (int k2 = 0; k2 < 2; ++k2)
#pragma unroll
    for (int Rf = 0; Rf < 8; ++Rf) {
      int kv = Rf * 16 + l15;
      half8 ka = *(const half8*)(Kb + kv * 64 + k2 * 32 + ((g4 + kv) & 3) * 8);
      sacc[Rf][0] = MFMA16(ka, qb[0][k2], sacc[Rf][0]);
      sacc[Rf][1] = MFMA16(ka, qb[1][k2], sacc[Rf][1]);
    }
  // softmax over kv (S^T rows): lane-local 32 + xor 16,32
  float rmax[2] = {-1e30f, -1e30f};
#pragma unroll
  for (int Rf = 0; Rf < 8; ++Rf)
#pragma unroll
    for (int cf = 0; cf < 2; ++cf)
#pragma unroll
      for (int r = 0; r < 4; ++r) rmax[cf] = fmaxf(rmax[cf], sacc[Rf][cf][r]);
#pragma unroll
  for (int cf = 0; cf < 2; ++cf) {
    rmax[cf] = fmaxf(rmax[cf], __shfl_xor(rmax[cf], 16, 64));
    rmax[cf] = fmaxf(rmax[cf], __shfl_xor(rmax[cf], 32, 64));
  }
  float rsum[2] = {0.f, 0.f};
#pragma unroll
  for (int Rf = 0; Rf < 8; ++Rf)
#pragma unroll
    for (int cf = 0; cf < 2; ++cf)
#pragma unroll
      for (int r = 0; r < 4; ++r) {
        float p = exp2f(sacc[Rf][cf][r] - rmax[cf]);
        sacc[Rf][cf][r] = p;
        rsum[cf] += p;
      }
#pragma unroll
  for (int cf = 0; cf < 2; ++cf) {
    rsum[cf] += __shfl_xor(rsum[cf], 16, 64);
    rsum[cf] += __shfl_xor(rsum[cf], 32, 64);
    rsum[cf] = 1.0f / rsum[cf];
  }
  // O^T = V^T * P^T  (S^T C-frags feed P^T B-frags directly)
  f32x4 oacc[4][2] = {};
#pragma unroll
  for (int kb = 0; kb < 4; ++kb) {
    half8 pb[2];
#pragma unroll
    for (int cf = 0; cf < 2; ++cf) {
      half8 tt;
#pragma unroll
      for (int hb = 0; hb < 8; ++hb)
        tt[hb] = (h16)sacc[2 * kb + (hb >> 2)][cf][hb & 3];
      pb[cf] = tt;
    }
#pragma unroll
    for (int dR = 0; dR < 4; ++dR) {
      int dd = dR * 16 + l15;
      half8 va = *(const half8*)(Vb + dd * 128 + kb * 32 + ((g4 + dd) & 3) * 8);
      oacc[dR][0] = MFMA16(va, pb[0], oacc[dR][0]);
      oacc[dR][1] = MFMA16(va, pb[1], oacc[dR][1]);
    }
  }
  // store ao (swizzled A-layout for outproj), half4 per frag
#pragma unroll
  for (int dR = 0; dR < 4; ++dR)
#pragma unroll
    for (int cf = 0; cf < 2; ++cf) {
      int tok127 = w * 32 + cf * 16 + l15;
      size_t token = (size_t)blk * 128 + tok127;
      half4 v4;
#pragma unroll
      for (int r = 0; r < 4; ++r) v4[r] = (h16)(oacc[dR][cf][r] * rsum[cf]);
      *(half4*)&ao[token * 1024 + (2 * head + (dR >> 1)) * 32 +
                   ((g4 + tok127) & 3) * 8 + (dR & 1) * 4] = v4;
    }
}

// ----------------- kernel 5: out = ao * Wo^T + bo (fp32) -------------------
__global__ __launch_bounds__(256) void k_outproj(
    const h16* __restrict__ ao, const h16* __restrict__ Wto,
    const float* __restrict__ bo, float* __restrict__ out) {
  __shared__ h16 A[128 * 32];
  __shared__ h16 B[128 * 32];
  int bid = blockIdx.x;                      // 1024
  int tile = (bid & 7) * 128 + (bid >> 3);
  int mt = tile >> 3, nt = tile & 7;
  size_t m0 = (size_t)mt * 128;
  int n0 = nt * 128;
  int tid = threadIdx.x, w = tid >> 6, lane = tid & 63;
  int l15 = lane & 15, g4 = lane >> 4;
  int wr = w >> 1, wc = w & 1;
  f32x4 acc[4][4] = {};
  for (int kt = 0; kt < 32; ++kt) {
#pragma unroll
    for (int j = 0; j < 2; ++j) {
      int s = j * 256 + tid;
      int r = s >> 2, t4 = s & 3;
      gload16(ao + (m0 + r) * 1024 + kt * 32 + t4 * 8, &A[(j * 256 + w * 64) * 8]);
      gload16(Wto + (size_t)(n0 + r) * 1024 + kt * 32 + t4 * 8,
              &B[(j * 256 + w * 64) * 8]);
    }
    __syncthreads();
    half8 a[4], b[4];
#pragma unroll
    for (int mi = 0; mi < 4; ++mi)
      a[mi] = *(const half8*)&A[(wr * 64 + mi * 16 + l15) * 32 + ((g4 + l15) & 3) * 8];
#pragma unroll
    for (int nj = 0; nj < 4; ++nj)
      b[nj] = *(const half8*)&B[(wc * 64 + nj * 16 + l15) * 32 + ((g4 + l15) & 3) * 8];
#pragma unroll
    for (int nj = 0; nj < 4; ++nj)
#pragma unroll
      for (int mi = 0; mi < 4; ++mi) acc[mi][nj] = MFMA16(a[mi], b[nj], acc[mi][nj]);
    __syncthreads();
  }
#pragma unroll
  for (int mi = 0; mi < 4; ++mi)
#pragma unroll
    for (int nj = 0; nj < 4; ++nj) {
      int col = n0 + wc * 64 + nj * 16 + l15;
      float bb = bo[col];
      size_t rowb = m0 + wr * 64 + mi * 16 + 4 * g4;
#pragma unroll
      for (int r = 0; r < 4; ++r)
        out[(rowb + r) * 1024 + col] = acc[mi][nj][r] + bb;
    }
}

// ---------------------------------------------------------------------------
extern "C" void kernel_launch(void* const* d_in, const int* in_sizes, int n_in,
                              void* d_out, int out_size, void* d_ws, size_t ws_size,
                              hipStream_t stream) {
  const float* x  = (const float*)d_in[0];
  const float* Wq = (const float*)d_in[1];
  const float* bq = (const float*)d_in[2];
  const float* Wk = (const float*)d_in[3];
  const float* bk = (const float*)d_in[4];
  const float* Wv = (const float*)d_in[5];
  const float* bv = (const float*)d_in[6];
  const float* Wo = (const float*)d_in[7];
  const float* bo = (const float*)d_in[8];
  float* out = (float*)d_out;

  char* ws = (char*)d_ws;                  // needs >= 136 MB
  h16* xh = (h16*)ws;                      // 32 MB (reused as ao after QKV GEMM)
  h16* wt = (h16*)(ws + (32u << 20));      // 8 MB: q,k,v,o consecutive
  h16* Qp = (h16*)(ws + (40u << 20));      // 32 MB
  h16* Kp = (h16*)(ws + (72u << 20));      // 32 MB
  h16* Vp = (h16*)(ws + (104u << 20));     // 32 MB
  h16* ao = xh;                            // alias: xh dead after k_gemm_qkv

  k_cvt_x<<<2048, 256, 0, stream>>>(x, xh);
  k_cvt_w<<<2048, 256, 0, stream>>>(Wq, Wk, Wv, Wo, wt);
  k_gemm_qkv<<<3072, 256, 0, stream>>>(xh, wt, bq, bk, bv, Qp, Kp, Vp);
  k_attn<<<2048, 256, 0, stream>>>(Qp, Kp, Vp, ao);
  k_outproj<<<1024, 256, 0, stream>>>(ao, wt + 3u * 1024 * 1024, bo, out);
}